// Round 14
// baseline (185.233 us; speedup 1.0000x reference)
//
#include <hip/hip_runtime.h>
#include <hip/hip_bf16.h>
#include <stdint.h>

typedef __bf16 bf16;
typedef __attribute__((ext_vector_type(4))) __bf16 bf16x4;
typedef __attribute__((ext_vector_type(8))) __bf16 bf16x8;
typedef __attribute__((ext_vector_type(4))) float f32x4;

#define MFMA16(a, b, c) __builtin_amdgcn_mfma_f32_16x16x32_bf16((a), (b), (c), 0, 0, 0)

// scale (1/sqrt(32)) * log2(e), folded into q at the gemm1 epilogue
#define QSC (0.17677669529663687f * 1.4426950408889634f)

__device__ __forceinline__ void async_cp16(const bf16* g, bf16* l) {
  __builtin_amdgcn_global_load_lds(
      (const __attribute__((address_space(1))) void*)g,
      (__attribute__((address_space(3))) void*)l, 16, 0, 0);
}

// ---------- fused prep: x cast (blocks 0..1023) | w_qkv^T (1024..1791) |
// ---------- w_proj^T (1792..2047). Transposes: fp32 (R x C) -> bf16 (C x R).
__global__ __launch_bounds__(256) void prep_k(const float* __restrict__ x,
                                              bf16* __restrict__ xb,
                                              const float* __restrict__ wqkv,
                                              bf16* __restrict__ wqkvT,
                                              const float* __restrict__ wproj,
                                              bf16* __restrict__ wprojT) {
  __shared__ bf16 t[64][65];
  const int bid = blockIdx.x;
  if (bid < 1024) {  // x cast, 4 elems/thread grid-stride
    int i = (bid * 256 + threadIdx.x) * 4;
    const int stride = 1024 * 256 * 4;
    for (; i < 4194304; i += stride) {
      const f32x4 f = *(const f32x4*)(x + i);
      bf16x4 o;
      o[0] = (bf16)f[0]; o[1] = (bf16)f[1]; o[2] = (bf16)f[2]; o[3] = (bf16)f[3];
      *(bf16x4*)(xb + i) = o;
    }
    return;
  }
  const float* in;
  bf16* out;
  int R, C, tb;
  if (bid < 1792) { in = wqkv; out = wqkvT; R = 1024; C = 3072; tb = bid - 1024; }
  else            { in = wproj; out = wprojT; R = 1024; C = 1024; tb = bid - 1792; }
  const int tilesx = C >> 6;
  const int bc = (tb % tilesx) * 64, br = (tb / tilesx) * 64;
  const int tx = threadIdx.x & 63, ty = threadIdx.x >> 6;
#pragma unroll
  for (int r = ty; r < 64; r += 4) t[r][tx] = (bf16)in[(br + r) * C + bc + tx];
  __syncthreads();
#pragma unroll
  for (int r = ty; r < 64; r += 4) out[(bc + r) * R + br + tx] = t[tx][r];
}

// ---------------- BMx128 bf16 GEMM, BK=64, BT is N-major (N x K) ----------------
// LDS rows chunk-rotated: 16B chunk c of row r at position (c+r)&7.
// MODE 0: fp32 store to C. MODE 1: qkv epilogue with RoPE + scatter (bf16);
// vT gets the attention pi-permutation on s within each 64-block (r8 comment).
template <int MODE, int BM>
__global__ __launch_bounds__(256) void gemm128(
    const bf16* __restrict__ A, const bf16* __restrict__ BT, int M, int N, int K,
    float* __restrict__ C, bf16* __restrict__ qws, bf16* __restrict__ kws,
    bf16* __restrict__ vT, const float* __restrict__ ropeC, const float* __restrict__ ropeS) {
  constexpr int MT = BM / 32;  // 16-row tiles per wave
  __shared__ __align__(16) bf16 As[BM * 64];
  __shared__ __align__(16) bf16 Bs[128 * 64];
  const int tid = threadIdx.x;
  const int lane = tid & 63, wave = tid >> 6;
  const int l16 = lane & 15, quad = lane >> 4;
  const int wm = (wave >> 1) * (BM / 2), wn = (wave & 1) * 64;
  const int bm = blockIdx.y, bn = blockIdx.x;

  const int srow = tid >> 3;
  const int schunk = ((tid & 7) - srow) & 7;
  const bf16* ag = A + (bm * BM + srow) * K + schunk * 8;
  const bf16* bg = BT + (bn * 128 + srow) * K + schunk * 8;
  bf16* la = &As[tid * 8];
  bf16* lb = &Bs[tid * 8];

  f32x4 acc[MT][4] = {};

  for (int k0 = 0; k0 < K; k0 += 64) {
    async_cp16(ag + k0, la);
    async_cp16(ag + 32 * K + k0, la + 2048);
    if (BM == 128) {
      async_cp16(ag + 64 * K + k0, la + 4096);
      async_cp16(ag + 96 * K + k0, la + 6144);
    }
    async_cp16(bg + k0, lb);
    async_cp16(bg + 32 * K + k0, lb + 2048);
    async_cp16(bg + 64 * K + k0, lb + 4096);
    async_cp16(bg + 96 * K + k0, lb + 6144);
    __syncthreads();
#pragma unroll
    for (int ks = 0; ks < 2; ++ks) {
      bf16x8 af[MT], bff[4];
#pragma unroll
      for (int t = 0; t < MT; ++t) {
        const int r = wm + t * 16 + l16;
        af[t] = *(const bf16x8*)&As[r * 64 + ((ks * 4 + quad + r) & 7) * 8];
      }
#pragma unroll
      for (int t = 0; t < 4; ++t) {
        const int r = wn + t * 16 + l16;
        bff[t] = *(const bf16x8*)&Bs[r * 64 + ((ks * 4 + quad + r) & 7) * 8];
      }
#pragma unroll
      for (int mt = 0; mt < MT; ++mt)
#pragma unroll
        for (int nt = 0; nt < 4; ++nt) acc[mt][nt] = MFMA16(af[mt], bff[nt], acc[mt][nt]);
    }
    __syncthreads();
  }

  if (MODE == 0) {
#pragma unroll
    for (int mt = 0; mt < MT; ++mt)
#pragma unroll
      for (int i = 0; i < 4; ++i) {
        const int row = bm * BM + wm + mt * 16 + quad * 4 + i;
#pragma unroll
        for (int nt = 0; nt < 4; ++nt) {
          const int col = bn * 128 + wn + nt * 16 + l16;
          C[row * N + col] = acc[mt][nt][i];
        }
      }
  } else {
    bf16* tb = &Bs[wave * 512];  // 16 x 16 tile, stride 20 (conflict-free)
#pragma unroll
    for (int mt = 0; mt < MT; ++mt) {
      const int s0 = bm * BM + wm + mt * 16;  // = b*2048 + sbase, 16-aligned
      const int b = s0 >> 11, sbase = s0 & 2047;
#pragma unroll
      for (int nt = 0; nt < 4; ++nt) {
        const int colb = bn * 128 + wn + nt * 16;
        const int sec = colb >> 10, rem = colb & 1023;
        const int h = rem >> 6, d0 = rem & 63;
        if (sec < 2) {  // q or k: RoPE, bounce through LDS for b64 stores
          const int d = d0 + l16;
#pragma unroll
          for (int i = 0; i < 4; ++i) {
            const int s = sbase + quad * 4 + i;
            float v = acc[mt][nt][i];
            float pr = __shfl_xor(v, 1);  // partner dim d^1 (lane l16^1)
            float rot = (d & 1) ? pr : -pr;
            float rv = v * ropeC[s * 64 + d] + rot * ropeS[s * 64 + d];
            if (sec == 0) rv *= QSC;  // fold softmax scale*log2e into q
            tb[(quad * 4 + i) * 20 + l16] = (bf16)rv;
          }
          bf16* dst = ((sec == 0) ? qws : kws) + ((b * 16 + h) * 2048 + sbase) * 64 + d0;
          bf16x4 seg = *(const bf16x4*)&tb[l16 * 20 + quad * 4];
          *(bf16x4*)(dst + l16 * 64 + quad * 4) = seg;
        } else {  // v: store b64 to vT (d-major) at pi-permuted s position
          const int d = d0 + l16;
          const int s4 = sbase + quad * 4;
          const int a = (s4 >> 4) & 3;
          const int p = (s4 & ~63) | ((a >> 1) * 32 + quad * 8 + (a & 1) * 4);
          bf16x4 pk;
#pragma unroll
          for (int i = 0; i < 4; ++i) pk[i] = (bf16)acc[mt][nt][i];
          *(bf16x4*)(vT + ((b * 16 + h) * 64 + d) * 2048 + p) = pk;
        }
      }
    }
  }
}

// ---------------- dual-triangle attention (r13-verified body) ----------------
// SPLIT=0: grid 512 = bh(hi) x 16 qblk; full K; normalized write to aw.
// SPLIT=1: grid 1024 = (qblk*2+kh)*32 + bh (bh in low 5 bits -> blocks sharing
//   one head's K/V cluster onto one XCD's L2); each block does 16 of 32 jt
//   tiles, writes UNNORMALIZED o (bf16) + l (fp32) partials; merge_k divides.
template <int SPLIT>
__global__ __launch_bounds__(256) void attn_k(const bf16* __restrict__ qws,
                                              const bf16* __restrict__ kws,
                                              const bf16* __restrict__ vT,
                                              bf16* __restrict__ awA, bf16* __restrict__ pB,
                                              float* __restrict__ lA, float* __restrict__ lB) {
  __shared__ __align__(16) bf16 Ks[2][64 * 64];
  __shared__ __align__(16) bf16 Vs[2][64 * 64];
  const int tid = threadIdx.x;
  const int lane = tid & 63, wave = tid >> 6;
  const int l16 = lane & 15, quad = lane >> 4;
  int bh, qblk, kh;
  if (SPLIT) {
    bh = blockIdx.x & 31;
    const int q2 = blockIdx.x >> 5;
    qblk = q2 >> 1;
    kh = q2 & 1;
  } else {
    bh = blockIdx.x >> 4;
    qblk = blockIdx.x & 15;
    kh = 0;
  }
  const int b = bh >> 4, h = bh & 15;
  const int rbase = qblk * 128 + wave * 32;
  const int jt0 = kh * 16;
  const int jt1 = SPLIT ? jt0 + 16 : 32;

  const bf16* qb = qws + (bh * 2048 + rbase) * 64;
  const bf16* kb = kws + bh * 2048 * 64;
  const bf16* vb = vT + bh * 64 * 2048;

  const int r0 = wave * 16 + (lane >> 3);
  const int c0 = ((lane & 7) - r0) & 7;  // chunk rotation
  const bf16* kst0 = kb + r0 * 64 + c0 * 8;
  const bf16* kst1 = kb + (r0 + 8) * 64 + c0 * 8;
  const bf16* vst0 = vb + r0 * 2048 + c0 * 8;
  const bf16* vst1 = vb + (r0 + 8) * 2048 + c0 * 8;

#define STAGE(jtv)                                         \
  {                                                        \
    bf16* kdst = &Ks[(jtv) & 1][wave * 1024];              \
    bf16* vdst = &Vs[(jtv) & 1][wave * 1024];              \
    async_cp16(kst0 + (jtv) * 4096, kdst);                 \
    async_cp16(kst1 + (jtv) * 4096, kdst + 512);           \
    async_cp16(vst0 + (jtv) * 64, vdst);                   \
    async_cp16(vst1 + (jtv) * 64, vdst + 512);             \
  }

  bf16x8 qf[2][2];
#pragma unroll
  for (int g = 0; g < 2; ++g)
#pragma unroll
    for (int hf = 0; hf < 2; ++hf)
      qf[g][hf] = *(const bf16x8*)(qb + (g * 16 + l16) * 64 + hf * 32 + quad * 8);

  bf16x8 ones;
#pragma unroll
  for (int j = 0; j < 8; ++j) ones[j] = (bf16)1.0f;

  f32x4 o[2][4] = {};
  f32x4 o_l[2] = {};
  const f32x4 zz = {};
  const int tdw = rbase >> 6;  // jt<tdw pure-down, ==tdw mixed, >tdw pure-up

#define ATTN_BODY(TM, jt)                                                             \
  {                                                                                   \
    const bf16* Kb = Ks[(jt) & 1];                                                    \
    const bf16* Vb = Vs[(jt) & 1];                                                    \
    bf16x8 vf[2][4];                                                                  \
    _Pragma("unroll") for (int ks = 0; ks < 2; ++ks)                                  \
      _Pragma("unroll") for (int ntd = 0; ntd < 4; ++ntd)                             \
        vf[ks][ntd] = *(const bf16x8*)(Vb + (ntd * 16 + l16) * 64 +                   \
                                       ((ks * 4 + quad + l16) & 7) * 8);              \
    bf16x8 kfU[2][2], kfD[2][2];                                                      \
    _Pragma("unroll") for (int ks = 0; ks < 2; ++ks)                                  \
      _Pragma("unroll") for (int s = 0; s < 2; ++s) {                                 \
        const int ro = ((ks * 2 + s) * 16 + l16) * 64;                                \
        if (TM != 0) kfU[ks][s] = *(const bf16x8*)(Kb + ro + ((quad + l16) & 7) * 8); \
        if (TM != 2)                                                                  \
          kfD[ks][s] = *(const bf16x8*)(Kb + ro + ((4 + quad + l16) & 7) * 8);        \
      }                                                                               \
    if ((jt) + 1 < jt1) STAGE((jt) + 1)                                               \
    _Pragma("unroll") for (int ks = 0; ks < 2; ++ks) {                                \
      f32x4 sU[2][2], sD[2][2];                                                       \
      _Pragma("unroll") for (int s = 0; s < 2; ++s)                                   \
        _Pragma("unroll") for (int g = 0; g < 2; ++g) {                               \
          if (TM != 0) sU[s][g] = MFMA16(kfU[ks][s], qf[g][0], zz);                   \
          if (TM != 2) sD[s][g] = MFMA16(kfD[ks][s], qf[g][1], zz);                   \
        }                                                                             \
      _Pragma("unroll") for (int g = 0; g < 2; ++g) {                                 \
        bf16x8 af;                                                                    \
        _Pragma("unroll") for (int s = 0; s < 2; ++s)                                 \
          _Pragma("unroll") for (int r = 0; r < 4; ++r) {                             \
            float x;                                                                  \
            if (TM == 0) x = sD[s][g][r];                                             \
            else if (TM == 2) x = sU[s][g][r];                                        \
            else {                                                                    \
              const int jcol = (jt) * 64 + (ks * 2 + s) * 16 + quad * 4 + r;          \
              x = (jcol <= rbase + g * 16 + l16) ? sD[s][g][r] : sU[s][g][r];         \
            }                                                                         \
            af[s * 4 + r] = (bf16)__builtin_amdgcn_exp2f(x);                          \
          }                                                                           \
        o_l[g] = MFMA16(af, ones, o_l[g]);                                            \
        _Pragma("unroll") for (int ntd = 0; ntd < 4; ++ntd)                           \
            o[g][ntd] = MFMA16(af, vf[ks][ntd], o[g][ntd]);                           \
      }                                                                               \
    }                                                                                 \
  }

  STAGE(jt0)
  for (int jt = jt0; jt < jt1; ++jt) {
    asm volatile("s_waitcnt vmcnt(0)" ::: "memory");  // cross-wave DMA visibility
    __syncthreads();
    if (jt < tdw) ATTN_BODY(0, jt)
    else if (jt == tdw) ATTN_BODY(1, jt)
    else ATTN_BODY(2, jt)
  }
#undef ATTN_BODY
#undef STAGE

  if (SPLIT) {
    bf16* p = kh ? pB : awA;
    float* lp = kh ? lB : lA;
#pragma unroll
    for (int g = 0; g < 2; ++g) {
#pragma unroll
      for (int ntd = 0; ntd < 4; ++ntd)
#pragma unroll
        for (int r = 0; r < 4; ++r)
          p[(b * 2048 + rbase + g * 16 + quad * 4 + r) * 1024 + h * 64 + ntd * 16 + l16] =
              (bf16)o[g][ntd][r];
      if (l16 == 0)
#pragma unroll
        for (int r = 0; r < 4; ++r)
          lp[bh * 2048 + rbase + g * 16 + quad * 4 + r] = o_l[g][r];
    }
  } else {
#pragma unroll
    for (int g = 0; g < 2; ++g) {
      float ir[4];
#pragma unroll
      for (int r = 0; r < 4; ++r) ir[r] = __builtin_amdgcn_rcpf(o_l[g][r]);
#pragma unroll
      for (int ntd = 0; ntd < 4; ++ntd)
#pragma unroll
        for (int r = 0; r < 4; ++r)
          awA[(b * 2048 + rbase + g * 16 + quad * 4 + r) * 1024 + h * 64 + ntd * 16 + l16] =
              (bf16)(o[g][ntd][r] * ir[r]);
    }
  }
}

// ---------------- merge split-K partials: aw = (oA+oB)/(lA+lB) ----------------
__global__ __launch_bounds__(256) void merge_k(const bf16* __restrict__ pA,
                                               const bf16* __restrict__ pB,
                                               const float* __restrict__ lA,
                                               const float* __restrict__ lB,
                                               bf16* __restrict__ aw) {
  const int i = (blockIdx.x * 256 + threadIdx.x) * 4;  // 4 consecutive d, same row
  const int rowg = i >> 10;          // b*2048+s, 0..4095
  const int col = i & 1023;
  const int b = rowg >> 11, s = rowg & 2047, h = col >> 6;
  const int bh = b * 16 + h;
  const float l = lA[bh * 2048 + s] + lB[bh * 2048 + s];
  const float ir = __builtin_amdgcn_rcpf(l);
  const bf16x4 a = *(const bf16x4*)(pA + i);
  const bf16x4 bb = *(const bf16x4*)(pB + i);
  bf16x4 o;
#pragma unroll
  for (int j = 0; j < 4; ++j) o[j] = (bf16)(((float)a[j] + (float)bb[j]) * ir);
  *(bf16x4*)(aw + i) = o;
}

extern "C" void kernel_launch(void* const* d_in, const int* in_sizes, int n_in,
                              void* d_out, int out_size, void* d_ws, size_t ws_size,
                              hipStream_t stream) {
  const float* x = (const float*)d_in[0];       // (2,2048,1024) fp32
  const float* w_qkv = (const float*)d_in[1];   // (1024,3072) fp32
  const float* w_proj = (const float*)d_in[2];  // (1024,1024) fp32
  const float* ropeC = (const float*)d_in[3];   // (2048,64) fp32
  const float* ropeS = (const float*)d_in[4];   // (2048,64) fp32
  float* out = (float*)d_out;                   // (2,2048,1024) fp32

  char* ws = (char*)d_ws;
  bf16* xb = (bf16*)ws;     ws += (size_t)4194304 * 2;  // (4096,1024) bf16
  bf16* wqkvT = (bf16*)ws;  ws += (size_t)3145728 * 2;  // (3072,1024) N-major bf16
  bf16* wprojT = (bf16*)ws; ws += (size_t)1048576 * 2;  // (1024,1024) N-major bf16
  bf16* qws = (bf16*)ws;    ws += (size_t)4194304 * 2;  // (2,16,2048,64), q pre-scaled
  bf16* kws = (bf16*)ws;    ws += (size_t)4194304 * 2;  // (2,16,2048,64)
  bf16* vT = (bf16*)ws;     ws += (size_t)4194304 * 2;  // (2,16,64,2048), pi-permuted
  bf16* aw = (bf16*)ws;     ws += (size_t)4194304 * 2;  // (4096,1024)
  // split-K extras (only touched if ws_size admits them)
  bf16* pA = (bf16*)ws;     ws += (size_t)4194304 * 2;
  bf16* pB = (bf16*)ws;     ws += (size_t)4194304 * 2;
  float* lA = (float*)ws;   ws += (size_t)65536 * 4;
  float* lB = (float*)ws;   ws += (size_t)65536 * 4;
  const size_t need_split = (size_t)(ws - (char*)d_ws);
  const bool use_split = ws_size >= need_split;

  prep_k<<<2048, 256, 0, stream>>>(x, xb, w_qkv, wqkvT, w_proj, wprojT);
  gemm128<1, 128><<<dim3(3072 / 128, 4096 / 128), 256, 0, stream>>>(
      xb, wqkvT, 4096, 3072, 1024, nullptr, qws, kws, vT, ropeC, ropeS);
  if (use_split) {
    attn_k<1><<<1024, 256, 0, stream>>>(qws, kws, vT, pA, pB, lA, lB);
    merge_k<<<4096, 256, 0, stream>>>(pA, pB, lA, lB, aw);
  } else {
    attn_k<0><<<512, 256, 0, stream>>>(qws, kws, vT, aw, nullptr, nullptr, nullptr);
  }
  gemm128<0, 64><<<dim3(1024 / 128, 4096 / 64), 256, 0, stream>>>(
      aw, wprojT, 4096, 1024, 1024, out, nullptr, nullptr, nullptr, nullptr, nullptr);
}

// Round 15
// 182.820 us; speedup vs baseline: 1.0132x; 1.0132x over previous
//
#include <hip/hip_runtime.h>
#include <hip/hip_bf16.h>
#include <stdint.h>

typedef __bf16 bf16;
typedef __attribute__((ext_vector_type(4))) __bf16 bf16x4;
typedef __attribute__((ext_vector_type(8))) __bf16 bf16x8;
typedef __attribute__((ext_vector_type(4))) float f32x4;

#define MFMA16(a, b, c) __builtin_amdgcn_mfma_f32_16x16x32_bf16((a), (b), (c), 0, 0, 0)

// scale (1/sqrt(32)) * log2(e), folded into q at the gemm1 epilogue
#define QSC (0.17677669529663687f * 1.4426950408889634f)

__device__ __forceinline__ void async_cp16(const bf16* g, bf16* l) {
  __builtin_amdgcn_global_load_lds(
      (const __attribute__((address_space(1))) void*)g,
      (__attribute__((address_space(3))) void*)l, 16, 0, 0);
}

// ---------- fused prep: x cast (blocks 0..1023) | w_qkv^T (1024..1791) |
// ---------- w_proj^T (1792..2047). Transposes: fp32 (R x C) -> bf16 (C x R).
__global__ __launch_bounds__(256) void prep_k(const float* __restrict__ x,
                                              bf16* __restrict__ xb,
                                              const float* __restrict__ wqkv,
                                              bf16* __restrict__ wqkvT,
                                              const float* __restrict__ wproj,
                                              bf16* __restrict__ wprojT) {
  __shared__ bf16 t[64][65];
  const int bid = blockIdx.x;
  if (bid < 1024) {  // x cast, 4 elems/thread grid-stride
    int i = (bid * 256 + threadIdx.x) * 4;
    const int stride = 1024 * 256 * 4;
    for (; i < 4194304; i += stride) {
      const f32x4 f = *(const f32x4*)(x + i);
      bf16x4 o;
      o[0] = (bf16)f[0]; o[1] = (bf16)f[1]; o[2] = (bf16)f[2]; o[3] = (bf16)f[3];
      *(bf16x4*)(xb + i) = o;
    }
    return;
  }
  const float* in;
  bf16* out;
  int R, C, tb;
  if (bid < 1792) { in = wqkv; out = wqkvT; R = 1024; C = 3072; tb = bid - 1024; }
  else            { in = wproj; out = wprojT; R = 1024; C = 1024; tb = bid - 1792; }
  const int tilesx = C >> 6;
  const int bc = (tb % tilesx) * 64, br = (tb / tilesx) * 64;
  const int tx = threadIdx.x & 63, ty = threadIdx.x >> 6;
#pragma unroll
  for (int r = ty; r < 64; r += 4) t[r][tx] = (bf16)in[(br + r) * C + bc + tx];
  __syncthreads();
#pragma unroll
  for (int r = ty; r < 64; r += 4) out[(bc + r) * R + br + tx] = t[tx][r];
}

// ---------------- BMx128 bf16 GEMM, BK=32 DOUBLE-BUFFERED, one barrier/iter ----
// Pipeline (r10-attn-proven): STAGE(it+1) issued after this iter's frag reads,
// explicit s_waitcnt vmcnt(0) before each barrier -> DMA rides under the math,
// barrier never waits on a fresh DMA. LDS pair-rotation layout: 16B chunk c of
// row r at position ((r>>1)+c)&3 within the 64B row. Staging stays DMA-contiguous
// (global source permuted per lane); b128 frag reads hit each bank-group exactly
// 2x (free per m136). K accumulation order identical to BK=64 version.
// MODE 0: fp32 store to C. MODE 1: qkv epilogue with RoPE + scatter (bf16);
// vT gets the attention pi-permutation on s within each 64-block (r8 comment).
template <int MODE, int BM>
__global__ __launch_bounds__(256) void gemm128(
    const bf16* __restrict__ A, const bf16* __restrict__ BT, int M, int N, int K,
    float* __restrict__ C, bf16* __restrict__ qws, bf16* __restrict__ kws,
    bf16* __restrict__ vT, const float* __restrict__ ropeC, const float* __restrict__ ropeS) {
  constexpr int MT = BM / 32;  // 16-row tiles per wave
  __shared__ __align__(16) bf16 As[2][BM * 32];
  __shared__ __align__(16) bf16 Bs[2][128 * 32];
  const int tid = threadIdx.x;
  const int lane = tid & 63, wave = tid >> 6;
  const int l16 = lane & 15, quad = lane >> 4;
  const int wm = (wave >> 1) * (BM / 2), wn = (wave & 1) * 64;
  const int bm = blockIdx.y, bn = blockIdx.x;

  // staging: thread t owns LDS 16B unit t of a 4KB slab (64 rows x 64B).
  // LDS (row, pos): pos = ((row>>1) + chunk)&3  ->  global chunk = (pos-(row>>1))&3.
  const int srow = tid >> 2;
  const int schunk = ((tid & 3) - (srow >> 1)) & 3;
  const bf16* ag = A + (bm * BM + srow) * K + schunk * 8;
  const bf16* bg = BT + (bn * 128 + srow) * K + schunk * 8;

#define GSTAGE(k0v, buf)                                        \
  {                                                             \
    bf16* la = &As[buf][tid * 8];                               \
    bf16* lb = &Bs[buf][tid * 8];                               \
    async_cp16(ag + (k0v), la);                                 \
    if (BM == 128) async_cp16(ag + 64 * K + (k0v), la + 2048);  \
    async_cp16(bg + (k0v), lb);                                 \
    async_cp16(bg + 64 * K + (k0v), lb + 2048);                 \
  }

  f32x4 acc[MT][4] = {};
  const int niter = K >> 5;

  GSTAGE(0, 0)
  for (int it = 0; it < niter; ++it) {
    asm volatile("s_waitcnt vmcnt(0)" ::: "memory");  // DMA(it) retired (issued it-1)
    __syncthreads();
    const bf16* Ab = As[it & 1];
    const bf16* Bb = Bs[it & 1];
    bf16x8 af[MT], bff[4];
#pragma unroll
    for (int t = 0; t < MT; ++t) {
      const int r = wm + t * 16 + l16;
      af[t] = *(const bf16x8*)&Ab[r * 32 + ((((r >> 1) + quad) & 3) << 3)];
    }
#pragma unroll
    for (int t = 0; t < 4; ++t) {
      const int r = wn + t * 16 + l16;
      bff[t] = *(const bf16x8*)&Bb[r * 32 + ((((r >> 1) + quad) & 3) << 3)];
    }
    if (it + 1 < niter) GSTAGE((it + 1) * 32, (it + 1) & 1)
#pragma unroll
    for (int mt = 0; mt < MT; ++mt)
#pragma unroll
      for (int nt = 0; nt < 4; ++nt) acc[mt][nt] = MFMA16(af[mt], bff[nt], acc[mt][nt]);
  }
#undef GSTAGE

  if (MODE == 0) {
#pragma unroll
    for (int mt = 0; mt < MT; ++mt)
#pragma unroll
      for (int i = 0; i < 4; ++i) {
        const int row = bm * BM + wm + mt * 16 + quad * 4 + i;
#pragma unroll
        for (int nt = 0; nt < 4; ++nt) {
          const int col = bn * 128 + wn + nt * 16 + l16;
          C[row * N + col] = acc[mt][nt][i];
        }
      }
  } else {
    __syncthreads();  // all frag reads done before reusing Bs as bounce space
    bf16* tb = &Bs[0][wave * 512];  // 16 x 16 tile, stride 20 (conflict-free)
#pragma unroll
    for (int mt = 0; mt < MT; ++mt) {
      const int s0 = bm * BM + wm + mt * 16;  // = b*2048 + sbase, 16-aligned
      const int b = s0 >> 11, sbase = s0 & 2047;
#pragma unroll
      for (int nt = 0; nt < 4; ++nt) {
        const int colb = bn * 128 + wn + nt * 16;
        const int sec = colb >> 10, rem = colb & 1023;
        const int h = rem >> 6, d0 = rem & 63;
        if (sec < 2) {  // q or k: RoPE, bounce through LDS for b64 stores
          const int d = d0 + l16;
#pragma unroll
          for (int i = 0; i < 4; ++i) {
            const int s = sbase + quad * 4 + i;
            float v = acc[mt][nt][i];
            float pr = __shfl_xor(v, 1);  // partner dim d^1 (lane l16^1)
            float rot = (d & 1) ? pr : -pr;
            float rv = v * ropeC[s * 64 + d] + rot * ropeS[s * 64 + d];
            if (sec == 0) rv *= QSC;  // fold softmax scale*log2e into q
            tb[(quad * 4 + i) * 20 + l16] = (bf16)rv;
          }
          bf16* dst = ((sec == 0) ? qws : kws) + ((b * 16 + h) * 2048 + sbase) * 64 + d0;
          bf16x4 seg = *(const bf16x4*)&tb[l16 * 20 + quad * 4];
          *(bf16x4*)(dst + l16 * 64 + quad * 4) = seg;
        } else {  // v: store b64 to vT (d-major) at pi-permuted s position
          const int d = d0 + l16;
          const int s4 = sbase + quad * 4;
          const int a = (s4 >> 4) & 3;
          const int p = (s4 & ~63) | ((a >> 1) * 32 + quad * 8 + (a & 1) * 4);
          bf16x4 pk;
#pragma unroll
          for (int i = 0; i < 4; ++i) pk[i] = (bf16)acc[mt][nt][i];
          *(bf16x4*)(vT + ((b * 16 + h) * 64 + d) * 2048 + p) = pk;
        }
      }
    }
  }
}

// ---------------- dual-triangle attention (r13-verified body) ----------------
// SPLIT=0: grid 512 = bh(hi) x 16 qblk; full K; normalized write to aw.
// SPLIT=1: grid 1024 = (qblk*2+kh)*32 + bh (bh in low 5 bits -> L2 clustering);
//   each block does 16 of 32 jt tiles, writes UNNORMALIZED o (bf16) + l (fp32).
template <int SPLIT>
__global__ __launch_bounds__(256) void attn_k(const bf16* __restrict__ qws,
                                              const bf16* __restrict__ kws,
                                              const bf16* __restrict__ vT,
                                              bf16* __restrict__ awA, bf16* __restrict__ pB,
                                              float* __restrict__ lA, float* __restrict__ lB) {
  __shared__ __align__(16) bf16 Ks[2][64 * 64];
  __shared__ __align__(16) bf16 Vs[2][64 * 64];
  const int tid = threadIdx.x;
  const int lane = tid & 63, wave = tid >> 6;
  const int l16 = lane & 15, quad = lane >> 4;
  int bh, qblk, kh;
  if (SPLIT) {
    bh = blockIdx.x & 31;
    const int q2 = blockIdx.x >> 5;
    qblk = q2 >> 1;
    kh = q2 & 1;
  } else {
    bh = blockIdx.x >> 4;
    qblk = blockIdx.x & 15;
    kh = 0;
  }
  const int b = bh >> 4, h = bh & 15;
  const int rbase = qblk * 128 + wave * 32;
  const int jt0 = kh * 16;
  const int jt1 = SPLIT ? jt0 + 16 : 32;

  const bf16* qb = qws + (bh * 2048 + rbase) * 64;
  const bf16* kb = kws + bh * 2048 * 64;
  const bf16* vb = vT + bh * 64 * 2048;

  const int r0 = wave * 16 + (lane >> 3);
  const int c0 = ((lane & 7) - r0) & 7;  // chunk rotation
  const bf16* kst0 = kb + r0 * 64 + c0 * 8;
  const bf16* kst1 = kb + (r0 + 8) * 64 + c0 * 8;
  const bf16* vst0 = vb + r0 * 2048 + c0 * 8;
  const bf16* vst1 = vb + (r0 + 8) * 2048 + c0 * 8;

#define STAGE(jtv)                                         \
  {                                                        \
    bf16* kdst = &Ks[(jtv) & 1][wave * 1024];              \
    bf16* vdst = &Vs[(jtv) & 1][wave * 1024];              \
    async_cp16(kst0 + (jtv) * 4096, kdst);                 \
    async_cp16(kst1 + (jtv) * 4096, kdst + 512);           \
    async_cp16(vst0 + (jtv) * 64, vdst);                   \
    async_cp16(vst1 + (jtv) * 64, vdst + 512);             \
  }

  bf16x8 qf[2][2];
#pragma unroll
  for (int g = 0; g < 2; ++g)
#pragma unroll
    for (int hf = 0; hf < 2; ++hf)
      qf[g][hf] = *(const bf16x8*)(qb + (g * 16 + l16) * 64 + hf * 32 + quad * 8);

  bf16x8 ones;
#pragma unroll
  for (int j = 0; j < 8; ++j) ones[j] = (bf16)1.0f;

  f32x4 o[2][4] = {};
  f32x4 o_l[2] = {};
  const f32x4 zz = {};
  const int tdw = rbase >> 6;  // jt<tdw pure-down, ==tdw mixed, >tdw pure-up

#define ATTN_BODY(TM, jt)                                                             \
  {                                                                                   \
    const bf16* Kb = Ks[(jt) & 1];                                                    \
    const bf16* Vb = Vs[(jt) & 1];                                                    \
    bf16x8 vf[2][4];                                                                  \
    _Pragma("unroll") for (int ks = 0; ks < 2; ++ks)                                  \
      _Pragma("unroll") for (int ntd = 0; ntd < 4; ++ntd)                             \
        vf[ks][ntd] = *(const bf16x8*)(Vb + (ntd * 16 + l16) * 64 +                   \
                                       ((ks * 4 + quad + l16) & 7) * 8);              \
    bf16x8 kfU[2][2], kfD[2][2];                                                      \
    _Pragma("unroll") for (int ks = 0; ks < 2; ++ks)                                  \
      _Pragma("unroll") for (int s = 0; s < 2; ++s) {                                 \
        const int ro = ((ks * 2 + s) * 16 + l16) * 64;                                \
        if (TM != 0) kfU[ks][s] = *(const bf16x8*)(Kb + ro + ((quad + l16) & 7) * 8); \
        if (TM != 2)                                                                  \
          kfD[ks][s] = *(const bf16x8*)(Kb + ro + ((4 + quad + l16) & 7) * 8);        \
      }                                                                               \
    if ((jt) + 1 < jt1) STAGE((jt) + 1)                                               \
    _Pragma("unroll") for (int ks = 0; ks < 2; ++ks) {                                \
      f32x4 sU[2][2], sD[2][2];                                                       \
      _Pragma("unroll") for (int s = 0; s < 2; ++s)                                   \
        _Pragma("unroll") for (int g = 0; g < 2; ++g) {                               \
          if (TM != 0) sU[s][g] = MFMA16(kfU[ks][s], qf[g][0], zz);                   \
          if (TM != 2) sD[s][g] = MFMA16(kfD[ks][s], qf[g][1], zz);                   \
        }                                                                             \
      _Pragma("unroll") for (int g = 0; g < 2; ++g) {                                 \
        bf16x8 af;                                                                    \
        _Pragma("unroll") for (int s = 0; s < 2; ++s)                                 \
          _Pragma("unroll") for (int r = 0; r < 4; ++r) {                             \
            float x;                                                                  \
            if (TM == 0) x = sD[s][g][r];                                             \
            else if (TM == 2) x = sU[s][g][r];                                        \
            else {                                                                    \
              const int jcol = (jt) * 64 + (ks * 2 + s) * 16 + quad * 4 + r;          \
              x = (jcol <= rbase + g * 16 + l16) ? sD[s][g][r] : sU[s][g][r];         \
            }                                                                         \
            af[s * 4 + r] = (bf16)__builtin_amdgcn_exp2f(x);                          \
          }                                                                           \
        o_l[g] = MFMA16(af, ones, o_l[g]);                                            \
        _Pragma("unroll") for (int ntd = 0; ntd < 4; ++ntd)                           \
            o[g][ntd] = MFMA16(af, vf[ks][ntd], o[g][ntd]);                           \
      }                                                                               \
    }                                                                                 \
  }

  STAGE(jt0)
  for (int jt = jt0; jt < jt1; ++jt) {
    asm volatile("s_waitcnt vmcnt(0)" ::: "memory");  // cross-wave DMA visibility
    __syncthreads();
    if (jt < tdw) ATTN_BODY(0, jt)
    else if (jt == tdw) ATTN_BODY(1, jt)
    else ATTN_BODY(2, jt)
  }
#undef ATTN_BODY
#undef STAGE

  if (SPLIT) {
    bf16* p = kh ? pB : awA;
    float* lp = kh ? lB : lA;
#pragma unroll
    for (int g = 0; g < 2; ++g) {
#pragma unroll
      for (int ntd = 0; ntd < 4; ++ntd)
#pragma unroll
        for (int r = 0; r < 4; ++r)
          p[(b * 2048 + rbase + g * 16 + quad * 4 + r) * 1024 + h * 64 + ntd * 16 + l16] =
              (bf16)o[g][ntd][r];
      if (l16 == 0)
#pragma unroll
        for (int r = 0; r < 4; ++r)
          lp[bh * 2048 + rbase + g * 16 + quad * 4 + r] = o_l[g][r];
    }
  } else {
#pragma unroll
    for (int g = 0; g < 2; ++g) {
      float ir[4];
#pragma unroll
      for (int r = 0; r < 4; ++r) ir[r] = __builtin_amdgcn_rcpf(o_l[g][r]);
#pragma unroll
      for (int ntd = 0; ntd < 4; ++ntd)
#pragma unroll
        for (int r = 0; r < 4; ++r)
          awA[(b * 2048 + rbase + g * 16 + quad * 4 + r) * 1024 + h * 64 + ntd * 16 + l16] =
              (bf16)(o[g][ntd][r] * ir[r]);
    }
  }
}

// ---------------- merge split-K partials: aw = (oA+oB)/(lA+lB) ----------------
__global__ __launch_bounds__(256) void merge_k(const bf16* __restrict__ pA,
                                               const bf16* __restrict__ pB,
                                               const float* __restrict__ lA,
                                               const float* __restrict__ lB,
                                               bf16* __restrict__ aw) {
  const int i = (blockIdx.x * 256 + threadIdx.x) * 4;  // 4 consecutive d, same row
  const int rowg = i >> 10;          // b*2048+s, 0..4095
  const int col = i & 1023;
  const int b = rowg >> 11, s = rowg & 2047, h = col >> 6;
  const int bh = b * 16 + h;
  const float l = lA[bh * 2048 + s] + lB[bh * 2048 + s];
  const float ir = __builtin_amdgcn_rcpf(l);
  const bf16x4 a = *(const bf16x4*)(pA + i);
  const bf16x4 bb = *(const bf16x4*)(pB + i);
  bf16x4 o;
#pragma unroll
  for (int j = 0; j < 4; ++j) o[j] = (bf16)(((float)a[j] + (float)bb[j]) * ir);
  *(bf16x4*)(aw + i) = o;
}

extern "C" void kernel_launch(void* const* d_in, const int* in_sizes, int n_in,
                              void* d_out, int out_size, void* d_ws, size_t ws_size,
                              hipStream_t stream) {
  const float* x = (const float*)d_in[0];       // (2,2048,1024) fp32
  const float* w_qkv = (const float*)d_in[1];   // (1024,3072) fp32
  const float* w_proj = (const float*)d_in[2];  // (1024,1024) fp32
  const float* ropeC = (const float*)d_in[3];   // (2048,64) fp32
  const float* ropeS = (const float*)d_in[4];   // (2048,64) fp32
  float* out = (float*)d_out;                   // (2,2048,1024) fp32

  char* ws = (char*)d_ws;
  bf16* xb = (bf16*)ws;     ws += (size_t)4194304 * 2;  // (4096,1024) bf16
  bf16* wqkvT = (bf16*)ws;  ws += (size_t)3145728 * 2;  // (3072,1024) N-major bf16
  bf16* wprojT = (bf16*)ws; ws += (size_t)1048576 * 2;  // (1024,1024) N-major bf16
  bf16* qws = (bf16*)ws;    ws += (size_t)4194304 * 2;  // (2,16,2048,64), q pre-scaled
  bf16* kws = (bf16*)ws;    ws += (size_t)4194304 * 2;  // (2,16,2048,64)
  bf16* vT = (bf16*)ws;     ws += (size_t)4194304 * 2;  // (2,16,64,2048), pi-permuted
  bf16* aw = (bf16*)ws;     ws += (size_t)4194304 * 2;  // (4096,1024)
  // split-K extras (only touched if ws_size admits them)
  bf16* pA = (bf16*)ws;     ws += (size_t)4194304 * 2;
  bf16* pB = (bf16*)ws;     ws += (size_t)4194304 * 2;
  float* lA = (float*)ws;   ws += (size_t)65536 * 4;
  float* lB = (float*)ws;   ws += (size_t)65536 * 4;
  const size_t need_split = (size_t)(ws - (char*)d_ws);
  const bool use_split = ws_size >= need_split;

  prep_k<<<2048, 256, 0, stream>>>(x, xb, w_qkv, wqkvT, w_proj, wprojT);
  gemm128<1, 128><<<dim3(3072 / 128, 4096 / 128), 256, 0, stream>>>(
      xb, wqkvT, 4096, 3072, 1024, nullptr, qws, kws, vT, ropeC, ropeS);
  if (use_split) {
    attn_k<1><<<1024, 256, 0, stream>>>(qws, kws, vT, pA, pB, lA, lB);
    merge_k<<<4096, 256, 0, stream>>>(pA, pB, lA, lB, aw);
  } else {
    attn_k<0><<<512, 256, 0, stream>>>(qws, kws, vT, aw, nullptr, nullptr, nullptr);
  }
  gemm128<0, 64><<<dim3(1024 / 128, 4096 / 64), 256, 0, stream>>>(
      aw, wprojT, 4096, 1024, 1024, out, nullptr, nullptr, nullptr, nullptr, nullptr);
}

// Round 16
// 182.735 us; speedup vs baseline: 1.0137x; 1.0005x over previous
//
#include <hip/hip_runtime.h>
#include <hip/hip_bf16.h>
#include <stdint.h>

typedef __bf16 bf16;
typedef __attribute__((ext_vector_type(4))) __bf16 bf16x4;
typedef __attribute__((ext_vector_type(8))) __bf16 bf16x8;
typedef __attribute__((ext_vector_type(4))) float f32x4;

#define MFMA16(a, b, c) __builtin_amdgcn_mfma_f32_16x16x32_bf16((a), (b), (c), 0, 0, 0)

// scale (1/sqrt(32)) * log2(e), folded into q at the gemm1 epilogue
#define QSC (0.17677669529663687f * 1.4426950408889634f)

__device__ __forceinline__ void async_cp16(const bf16* g, bf16* l) {
  __builtin_amdgcn_global_load_lds(
      (const __attribute__((address_space(1))) void*)g,
      (__attribute__((address_space(3))) void*)l, 16, 0, 0);
}

// ---------- fused prep: x cast (blocks 0..1023) | w_qkv^T (1024..1791) |
// ---------- w_proj^T (1792..2047). Transposes: fp32 (R x C) -> bf16 (C x R).
__global__ __launch_bounds__(256) void prep_k(const float* __restrict__ x,
                                              bf16* __restrict__ xb,
                                              const float* __restrict__ wqkv,
                                              bf16* __restrict__ wqkvT,
                                              const float* __restrict__ wproj,
                                              bf16* __restrict__ wprojT) {
  __shared__ bf16 t[64][65];
  const int bid = blockIdx.x;
  if (bid < 1024) {  // x cast, 4 elems/thread grid-stride
    int i = (bid * 256 + threadIdx.x) * 4;
    const int stride = 1024 * 256 * 4;
    for (; i < 4194304; i += stride) {
      const f32x4 f = *(const f32x4*)(x + i);
      bf16x4 o;
      o[0] = (bf16)f[0]; o[1] = (bf16)f[1]; o[2] = (bf16)f[2]; o[3] = (bf16)f[3];
      *(bf16x4*)(xb + i) = o;
    }
    return;
  }
  const float* in;
  bf16* out;
  int R, C, tb;
  if (bid < 1792) { in = wqkv; out = wqkvT; R = 1024; C = 3072; tb = bid - 1024; }
  else            { in = wproj; out = wprojT; R = 1024; C = 1024; tb = bid - 1792; }
  const int tilesx = C >> 6;
  const int bc = (tb % tilesx) * 64, br = (tb / tilesx) * 64;
  const int tx = threadIdx.x & 63, ty = threadIdx.x >> 6;
#pragma unroll
  for (int r = ty; r < 64; r += 4) t[r][tx] = (bf16)in[(br + r) * C + bc + tx];
  __syncthreads();
#pragma unroll
  for (int r = ty; r < 64; r += 4) out[(bc + r) * R + br + tx] = t[tx][r];
}

// ---------------- BMx128 bf16 GEMM, BK=32, 3-DEEP pipeline, fine vmcnt ----
// During iter it we issue STAGE(it+2); at the top of iter it we wait
// s_waitcnt vmcnt(SI) (SI = insts of the newest stage) -> stage(it) is
// guaranteed retired while stage(it+1) stays in flight. Prefetch distance =
// 2 iterations of math (~700cy) >= DMA latency, so the barrier never blocks
// on memory (AITER-style never-vmcnt(0) K-loop). LDS pair-rotation layout:
// 16B chunk c of row r at position ((r>>1)+c)&3 (DMA-contiguous staging,
// 2-way bank alias on b128 frag reads - free per m136).
// MODE 0: fp32 store to C. MODE 1: qkv epilogue with RoPE + scatter (bf16);
// vT gets the attention pi-permutation on s within each 64-block (r8 comment).
template <int MODE, int BM>
__global__ __launch_bounds__(256) void gemm128(
    const bf16* __restrict__ A, const bf16* __restrict__ BT, int M, int N, int K,
    float* __restrict__ C, bf16* __restrict__ qws, bf16* __restrict__ kws,
    bf16* __restrict__ vT, const float* __restrict__ ropeC, const float* __restrict__ ropeS) {
  constexpr int MT = BM / 32;  // 16-row tiles per wave
  __shared__ __align__(16) bf16 As[3][BM * 32];
  __shared__ __align__(16) bf16 Bs[3][128 * 32];
  const int tid = threadIdx.x;
  const int lane = tid & 63, wave = tid >> 6;
  const int l16 = lane & 15, quad = lane >> 4;
  const int wm = (wave >> 1) * (BM / 2), wn = (wave & 1) * 64;
  const int bm = blockIdx.y, bn = blockIdx.x;

  // staging: thread t owns LDS 16B unit t of a 4KB slab (64 rows x 64B).
  // LDS (row, pos): pos = ((row>>1) + chunk)&3  ->  global chunk = (pos-(row>>1))&3.
  const int srow = tid >> 2;
  const int schunk = ((tid & 3) - (srow >> 1)) & 3;
  const bf16* ag = A + (bm * BM + srow) * K + schunk * 8;
  const bf16* bg = BT + (bn * 128 + srow) * K + schunk * 8;

#define GSTAGE(k0v, buf)                                        \
  {                                                             \
    bf16* la = &As[buf][tid * 8];                               \
    bf16* lb = &Bs[buf][tid * 8];                               \
    async_cp16(ag + (k0v), la);                                 \
    if (BM == 128) async_cp16(ag + 64 * K + (k0v), la + 2048);  \
    async_cp16(bg + (k0v), lb);                                 \
    async_cp16(bg + 64 * K + (k0v), lb + 2048);                 \
  }

  f32x4 acc[MT][4] = {};
  const int niter = K >> 5;

  GSTAGE(0, 0)
  GSTAGE(32, 1)
  int buf = 0;
  for (int it = 0; it < niter; ++it) {
    // allow the newest stage (it+1) to stay in flight; stage(it) must be done
    if (BM == 128)
      asm volatile("s_waitcnt vmcnt(4)" ::: "memory");
    else
      asm volatile("s_waitcnt vmcnt(3)" ::: "memory");
    __syncthreads();
    const bf16* Ab = As[buf];
    const bf16* Bb = Bs[buf];
    bf16x8 af[MT], bff[4];
#pragma unroll
    for (int t = 0; t < MT; ++t) {
      const int r = wm + t * 16 + l16;
      af[t] = *(const bf16x8*)&Ab[r * 32 + ((((r >> 1) + quad) & 3) << 3)];
    }
#pragma unroll
    for (int t = 0; t < 4; ++t) {
      const int r = wn + t * 16 + l16;
      bff[t] = *(const bf16x8*)&Bb[r * 32 + ((((r >> 1) + quad) & 3) << 3)];
    }
    if (it + 2 < niter) {
      const int nb = (buf + 2 >= 3) ? buf - 1 : buf + 2;
      GSTAGE((it + 2) * 32, nb)
    }
#pragma unroll
    for (int mt = 0; mt < MT; ++mt)
#pragma unroll
      for (int nt = 0; nt < 4; ++nt) acc[mt][nt] = MFMA16(af[mt], bff[nt], acc[mt][nt]);
    buf = (buf + 1 == 3) ? 0 : buf + 1;
  }
#undef GSTAGE

  if (MODE == 0) {
#pragma unroll
    for (int mt = 0; mt < MT; ++mt)
#pragma unroll
      for (int i = 0; i < 4; ++i) {
        const int row = bm * BM + wm + mt * 16 + quad * 4 + i;
#pragma unroll
        for (int nt = 0; nt < 4; ++nt) {
          const int col = bn * 128 + wn + nt * 16 + l16;
          C[row * N + col] = acc[mt][nt][i];
        }
      }
  } else {
    __syncthreads();  // all frag reads done before reusing Bs as bounce space
    bf16* tb = &Bs[0][wave * 512];  // 16 x 16 tile, stride 20 (conflict-free)
#pragma unroll
    for (int mt = 0; mt < MT; ++mt) {
      const int s0 = bm * BM + wm + mt * 16;  // = b*2048 + sbase, 16-aligned
      const int b = s0 >> 11, sbase = s0 & 2047;
#pragma unroll
      for (int nt = 0; nt < 4; ++nt) {
        const int colb = bn * 128 + wn + nt * 16;
        const int sec = colb >> 10, rem = colb & 1023;
        const int h = rem >> 6, d0 = rem & 63;
        if (sec < 2) {  // q or k: RoPE, bounce through LDS for b64 stores
          const int d = d0 + l16;
#pragma unroll
          for (int i = 0; i < 4; ++i) {
            const int s = sbase + quad * 4 + i;
            float v = acc[mt][nt][i];
            float pr = __shfl_xor(v, 1);  // partner dim d^1 (lane l16^1)
            float rot = (d & 1) ? pr : -pr;
            float rv = v * ropeC[s * 64 + d] + rot * ropeS[s * 64 + d];
            if (sec == 0) rv *= QSC;  // fold softmax scale*log2e into q
            tb[(quad * 4 + i) * 20 + l16] = (bf16)rv;
          }
          bf16* dst = ((sec == 0) ? qws : kws) + ((b * 16 + h) * 2048 + sbase) * 64 + d0;
          bf16x4 seg = *(const bf16x4*)&tb[l16 * 20 + quad * 4];
          *(bf16x4*)(dst + l16 * 64 + quad * 4) = seg;
        } else {  // v: store b64 to vT (d-major) at pi-permuted s position
          const int d = d0 + l16;
          const int s4 = sbase + quad * 4;
          const int a = (s4 >> 4) & 3;
          const int p = (s4 & ~63) | ((a >> 1) * 32 + quad * 8 + (a & 1) * 4);
          bf16x4 pk;
#pragma unroll
          for (int i = 0; i < 4; ++i) pk[i] = (bf16)acc[mt][nt][i];
          *(bf16x4*)(vT + ((b * 16 + h) * 64 + d) * 2048 + p) = pk;
        }
      }
    }
  }
}

// ---------------- dual-triangle attention (r13-verified body) ----------------
// SPLIT=0: grid 512 = bh(hi) x 16 qblk; full K; normalized write to aw.
// SPLIT=1: grid 1024 = (qblk*2+kh)*32 + bh (bh in low 5 bits -> L2 clustering);
//   each block does 16 of 32 jt tiles, writes UNNORMALIZED o (bf16) + l (fp32).
template <int SPLIT>
__global__ __launch_bounds__(256) void attn_k(const bf16* __restrict__ qws,
                                              const bf16* __restrict__ kws,
                                              const bf16* __restrict__ vT,
                                              bf16* __restrict__ awA, bf16* __restrict__ pB,
                                              float* __restrict__ lA, float* __restrict__ lB) {
  __shared__ __align__(16) bf16 Ks[2][64 * 64];
  __shared__ __align__(16) bf16 Vs[2][64 * 64];
  const int tid = threadIdx.x;
  const int lane = tid & 63, wave = tid >> 6;
  const int l16 = lane & 15, quad = lane >> 4;
  int bh, qblk, kh;
  if (SPLIT) {
    bh = blockIdx.x & 31;
    const int q2 = blockIdx.x >> 5;
    qblk = q2 >> 1;
    kh = q2 & 1;
  } else {
    bh = blockIdx.x >> 4;
    qblk = blockIdx.x & 15;
    kh = 0;
  }
  const int b = bh >> 4, h = bh & 15;
  const int rbase = qblk * 128 + wave * 32;
  const int jt0 = kh * 16;
  const int jt1 = SPLIT ? jt0 + 16 : 32;

  const bf16* qb = qws + (bh * 2048 + rbase) * 64;
  const bf16* kb = kws + bh * 2048 * 64;
  const bf16* vb = vT + bh * 64 * 2048;

  const int r0 = wave * 16 + (lane >> 3);
  const int c0 = ((lane & 7) - r0) & 7;  // chunk rotation
  const bf16* kst0 = kb + r0 * 64 + c0 * 8;
  const bf16* kst1 = kb + (r0 + 8) * 64 + c0 * 8;
  const bf16* vst0 = vb + r0 * 2048 + c0 * 8;
  const bf16* vst1 = vb + (r0 + 8) * 2048 + c0 * 8;

#define STAGE(jtv)                                         \
  {                                                        \
    bf16* kdst = &Ks[(jtv) & 1][wave * 1024];              \
    bf16* vdst = &Vs[(jtv) & 1][wave * 1024];              \
    async_cp16(kst0 + (jtv) * 4096, kdst);                 \
    async_cp16(kst1 + (jtv) * 4096, kdst + 512);           \
    async_cp16(vst0 + (jtv) * 64, vdst);                   \
    async_cp16(vst1 + (jtv) * 64, vdst + 512);             \
  }

  bf16x8 qf[2][2];
#pragma unroll
  for (int g = 0; g < 2; ++g)
#pragma unroll
    for (int hf = 0; hf < 2; ++hf)
      qf[g][hf] = *(const bf16x8*)(qb + (g * 16 + l16) * 64 + hf * 32 + quad * 8);

  bf16x8 ones;
#pragma unroll
  for (int j = 0; j < 8; ++j) ones[j] = (bf16)1.0f;

  f32x4 o[2][4] = {};
  f32x4 o_l[2] = {};
  const f32x4 zz = {};
  const int tdw = rbase >> 6;  // jt<tdw pure-down, ==tdw mixed, >tdw pure-up

#define ATTN_BODY(TM, jt)                                                             \
  {                                                                                   \
    const bf16* Kb = Ks[(jt) & 1];                                                    \
    const bf16* Vb = Vs[(jt) & 1];                                                    \
    bf16x8 vf[2][4];                                                                  \
    _Pragma("unroll") for (int ks = 0; ks < 2; ++ks)                                  \
      _Pragma("unroll") for (int ntd = 0; ntd < 4; ++ntd)                             \
        vf[ks][ntd] = *(const bf16x8*)(Vb + (ntd * 16 + l16) * 64 +                   \
                                       ((ks * 4 + quad + l16) & 7) * 8);              \
    bf16x8 kfU[2][2], kfD[2][2];                                                      \
    _Pragma("unroll") for (int ks = 0; ks < 2; ++ks)                                  \
      _Pragma("unroll") for (int s = 0; s < 2; ++s) {                                 \
        const int ro = ((ks * 2 + s) * 16 + l16) * 64;                                \
        if (TM != 0) kfU[ks][s] = *(const bf16x8*)(Kb + ro + ((quad + l16) & 7) * 8); \
        if (TM != 2)                                                                  \
          kfD[ks][s] = *(const bf16x8*)(Kb + ro + ((4 + quad + l16) & 7) * 8);        \
      }                                                                               \
    if ((jt) + 1 < jt1) STAGE((jt) + 1)                                               \
    _Pragma("unroll") for (int ks = 0; ks < 2; ++ks) {                                \
      f32x4 sU[2][2], sD[2][2];                                                       \
      _Pragma("unroll") for (int s = 0; s < 2; ++s)                                   \
        _Pragma("unroll") for (int g = 0; g < 2; ++g) {                               \
          if (TM != 0) sU[s][g] = MFMA16(kfU[ks][s], qf[g][0], zz);                   \
          if (TM != 2) sD[s][g] = MFMA16(kfD[ks][s], qf[g][1], zz);                   \
        }                                                                             \
      _Pragma("unroll") for (int g = 0; g < 2; ++g) {                                 \
        bf16x8 af;                                                                    \
        _Pragma("unroll") for (int s = 0; s < 2; ++s)                                 \
          _Pragma("unroll") for (int r = 0; r < 4; ++r) {                             \
            float x;                                                                  \
            if (TM == 0) x = sD[s][g][r];                                             \
            else if (TM == 2) x = sU[s][g][r];                                        \
            else {                                                                    \
              const int jcol = (jt) * 64 + (ks * 2 + s) * 16 + quad * 4 + r;          \
              x = (jcol <= rbase + g * 16 + l16) ? sD[s][g][r] : sU[s][g][r];         \
            }                                                                         \
            af[s * 4 + r] = (bf16)__builtin_amdgcn_exp2f(x);                          \
          }                                                                           \
        o_l[g] = MFMA16(af, ones, o_l[g]);                                            \
        _Pragma("unroll") for (int ntd = 0; ntd < 4; ++ntd)                           \
            o[g][ntd] = MFMA16(af, vf[ks][ntd], o[g][ntd]);                           \
      }                                                                               \
    }                                                                                 \
  }

  STAGE(jt0)
  for (int jt = jt0; jt < jt1; ++jt) {
    asm volatile("s_waitcnt vmcnt(0)" ::: "memory");  // cross-wave DMA visibility
    __syncthreads();
    if (jt < tdw) ATTN_BODY(0, jt)
    else if (jt == tdw) ATTN_BODY(1, jt)
    else ATTN_BODY(2, jt)
  }
#undef ATTN_BODY
#undef STAGE

  if (SPLIT) {
    bf16* p = kh ? pB : awA;
    float* lp = kh ? lB : lA;
#pragma unroll
    for (int g = 0; g < 2; ++g) {
#pragma unroll
      for (int ntd = 0; ntd < 4; ++ntd)
#pragma unroll
        for (int r = 0; r < 4; ++r)
          p[(b * 2048 + rbase + g * 16 + quad * 4 + r) * 1024 + h * 64 + ntd * 16 + l16] =
              (bf16)o[g][ntd][r];
      if (l16 == 0)
#pragma unroll
        for (int r = 0; r < 4; ++r)
          lp[bh * 2048 + rbase + g * 16 + quad * 4 + r] = o_l[g][r];
    }
  } else {
#pragma unroll
    for (int g = 0; g < 2; ++g) {
      float ir[4];
#pragma unroll
      for (int r = 0; r < 4; ++r) ir[r] = __builtin_amdgcn_rcpf(o_l[g][r]);
#pragma unroll
      for (int ntd = 0; ntd < 4; ++ntd)
#pragma unroll
        for (int r = 0; r < 4; ++r)
          awA[(b * 2048 + rbase + g * 16 + quad * 4 + r) * 1024 + h * 64 + ntd * 16 + l16] =
              (bf16)(o[g][ntd][r] * ir[r]);
    }
  }
}

// ---------------- merge split-K partials: aw = (oA+oB)/(lA+lB) ----------------
__global__ __launch_bounds__(256) void merge_k(const bf16* __restrict__ pA,
                                               const bf16* __restrict__ pB,
                                               const float* __restrict__ lA,
                                               const float* __restrict__ lB,
                                               bf16* __restrict__ aw) {
  const int i = (blockIdx.x * 256 + threadIdx.x) * 4;  // 4 consecutive d, same row
  const int rowg = i >> 10;          // b*2048+s, 0..4095
  const int col = i & 1023;
  const int b = rowg >> 11, s = rowg & 2047, h = col >> 6;
  const int bh = b * 16 + h;
  const float l = lA[bh * 2048 + s] + lB[bh * 2048 + s];
  const float ir = __builtin_amdgcn_rcpf(l);
  const bf16x4 a = *(const bf16x4*)(pA + i);
  const bf16x4 bb = *(const bf16x4*)(pB + i);
  bf16x4 o;
#pragma unroll
  for (int j = 0; j < 4; ++j) o[j] = (bf16)(((float)a[j] + (float)bb[j]) * ir);
  *(bf16x4*)(aw + i) = o;
}

extern "C" void kernel_launch(void* const* d_in, const int* in_sizes, int n_in,
                              void* d_out, int out_size, void* d_ws, size_t ws_size,
                              hipStream_t stream) {
  const float* x = (const float*)d_in[0];       // (2,2048,1024) fp32
  const float* w_qkv = (const float*)d_in[1];   // (1024,3072) fp32
  const float* w_proj = (const float*)d_in[2];  // (1024,1024) fp32
  const float* ropeC = (const float*)d_in[3];   // (2048,64) fp32
  const float* ropeS = (const float*)d_in[4];   // (2048,64) fp32
  float* out = (float*)d_out;                   // (2,2048,1024) fp32

  char* ws = (char*)d_ws;
  bf16* xb = (bf16*)ws;     ws += (size_t)4194304 * 2;  // (4096,1024) bf16
  bf16* wqkvT = (bf16*)ws;  ws += (size_t)3145728 * 2;  // (3072,1024) N-major bf16
  bf16* wprojT = (bf16*)ws; ws += (size_t)1048576 * 2;  // (1024,1024) N-major bf16
  bf16* qws = (bf16*)ws;    ws += (size_t)4194304 * 2;  // (2,16,2048,64), q pre-scaled
  bf16* kws = (bf16*)ws;    ws += (size_t)4194304 * 2;  // (2,16,2048,64)
  bf16* vT = (bf16*)ws;     ws += (size_t)4194304 * 2;  // (2,16,64,2048), pi-permuted
  bf16* aw = (bf16*)ws;     ws += (size_t)4194304 * 2;  // (4096,1024)
  // split-K extras (only touched if ws_size admits them)
  bf16* pA = (bf16*)ws;     ws += (size_t)4194304 * 2;
  bf16* pB = (bf16*)ws;     ws += (size_t)4194304 * 2;
  float* lA = (float*)ws;   ws += (size_t)65536 * 4;
  float* lB = (float*)ws;   ws += (size_t)65536 * 4;
  const size_t need_split = (size_t)(ws - (char*)d_ws);
  const bool use_split = ws_size >= need_split;

  prep_k<<<2048, 256, 0, stream>>>(x, xb, w_qkv, wqkvT, w_proj, wprojT);
  gemm128<1, 128><<<dim3(3072 / 128, 4096 / 128), 256, 0, stream>>>(
      xb, wqkvT, 4096, 3072, 1024, nullptr, qws, kws, vT, ropeC, ropeS);
  if (use_split) {
    attn_k<1><<<1024, 256, 0, stream>>>(qws, kws, vT, pA, pB, lA, lB);
    merge_k<<<4096, 256, 0, stream>>>(pA, pB, lA, lB, aw);
  } else {
    attn_k<0><<<512, 256, 0, stream>>>(qws, kws, vT, aw, nullptr, nullptr, nullptr);
  }
  gemm128<0, 64><<<dim3(1024 / 128, 4096 / 64), 256, 0, stream>>>(
      aw, wprojT, 4096, 1024, 1024, out, nullptr, nullptr, nullptr, nullptr, nullptr);
}